// Round 1
// baseline (367.661 us; speedup 1.0000x reference)
//
#include <hip/hip_runtime.h>

// Problem constants (match reference)
#define BB 8
#define NN 65536
#define DD 192
#define EPSV 1e-5f

// d_out layout: dss [B*N] | nss [B*N*3] | loss [1]
// One thread per point: 3 coalesced pss reads, 8-corner scattered gather,
// trilinear value + finite-difference normals, wave-reduced loss atomic.

__global__ __launch_bounds__(256) void tri_sdf_kernel(
    const float* __restrict__ pss,    // [B,3,N]
    const float* __restrict__ grid,   // [B,D,D,D]
    const float* __restrict__ first,  // [B,3]
    const float* __restrict__ coef,   // [B,3]
    const float* __restrict__ maxl,   // [B,3]
    float* __restrict__ dss,          // [B*N]
    float* __restrict__ nss,          // [B*N,3]
    float* __restrict__ loss)         // [1]
{
    const int t = blockIdx.x * blockDim.x + threadIdx.x;   // 0 .. B*N-1
    const int b = t >> 16;            // N == 65536
    const int n = t & (NN - 1);

    // --- load point (coalesced: stride-N between components) ---
    const float* pb = pss + (size_t)b * 3 * NN + n;
    const float px = pb[0];
    const float py = pb[NN];
    const float pz = pb[2 * NN];

    // --- per-batch transform params (tiny, L1/L2 broadcast) ---
    const float fx_full = fmaxf(fminf((px - first[3*b+0]) * coef[3*b+0], maxl[3*b+0]), 0.0f);
    const float fy_full = fmaxf(fminf((py - first[3*b+1]) * coef[3*b+1], maxl[3*b+1]), 0.0f);
    const float fz_full = fmaxf(fminf((pz - first[3*b+2]) * coef[3*b+2], maxl[3*b+2]), 0.0f);

    const int bx = (int)floorf(fx_full);
    const int by = (int)floorf(fy_full);
    const int bz = (int)floorf(fz_full);
    const float fx = fx_full - (float)bx;
    const float fy = fy_full - (float)by;
    const float fz = fz_full - (float)bz;

    // --- 8-corner gather: c_{i,j,k} = grid[b][bx+i][by+j][bz+k] ---
    const float* g = grid + (size_t)b * DD * DD * DD
                          + ((size_t)bx * DD + by) * DD + bz;
    // issue all 8 loads up front for MLP
    const float c000 = g[0];
    const float c001 = g[1];
    const float c010 = g[DD];
    const float c011 = g[DD + 1];
    const float c100 = g[DD * DD];
    const float c101 = g[DD * DD + 1];
    const float c110 = g[DD * DD + DD];
    const float c111 = g[DD * DD + DD + 1];

    const float wx0 = 1.0f - fx, wx1 = fx;
    const float wy0 = 1.0f - fy, wy1 = fy;
    const float wz0 = 1.0f - fz, wz1 = fz;

    // trilinear value
    const float d00 = wz0 * c000 + wz1 * c001;
    const float d01 = wz0 * c010 + wz1 * c011;
    const float d10 = wz0 * c100 + wz1 * c101;
    const float d11 = wz0 * c110 + wz1 * c111;
    const float d0  = wy0 * d00 + wy1 * d01;
    const float d1  = wy0 * d10 + wy1 * d11;
    const float dv  = wx0 * d0 + wx1 * d1;

    // finite-difference normals (match reference einsums exactly)
    const float nz = wx0 * (wy0 * (c001 - c000) + wy1 * (c011 - c010))
                   + wx1 * (wy0 * (c101 - c100) + wy1 * (c111 - c110));
    const float ny = wx0 * (wz0 * (c010 - c000) + wz1 * (c011 - c001))
                   + wx1 * (wz0 * (c110 - c100) + wz1 * (c111 - c101));
    const float nx = wy0 * (wz0 * (c100 - c000) + wz1 * (c101 - c001))
                   + wy1 * (wz0 * (c110 - c010) + wz1 * (c111 - c011));

    const float nrm = sqrtf(nx * nx + ny * ny + nz * nz);
    const float inv = 1.0f / fmaxf(nrm, EPSV);

    // --- stores ---
    dss[t] = dv;
    float* np_ = nss + (size_t)t * 3;
    np_[0] = nx * inv;
    np_[1] = ny * inv;
    np_[2] = nz * inv;

    // --- loss: -sum(min(dss, 0)) ; wave64 shuffle reduce, 1 atomic/wave ---
    float lp = fminf(dv, 0.0f);
    #pragma unroll
    for (int off = 32; off > 0; off >>= 1)
        lp += __shfl_down(lp, off, 64);
    if ((threadIdx.x & 63) == 0)
        atomicAdd(loss, -lp);
}

extern "C" void kernel_launch(void* const* d_in, const int* in_sizes, int n_in,
                              void* d_out, int out_size, void* d_ws, size_t ws_size,
                              hipStream_t stream) {
    const float* pss   = (const float*)d_in[0];
    const float* grid  = (const float*)d_in[1];
    const float* first = (const float*)d_in[2];
    const float* coef  = (const float*)d_in[3];
    const float* maxl  = (const float*)d_in[4];

    float* out  = (float*)d_out;
    float* dss  = out;                          // B*N
    float* nss  = out + (size_t)BB * NN;        // B*N*3
    float* loss = out + (size_t)4 * BB * NN;    // 1

    // harness poisons d_out with 0xAA before each timed replay — zero the
    // loss accumulator (memset node is graph-capture safe)
    hipMemsetAsync(loss, 0, sizeof(float), stream);

    const int threads = 256;
    const int blocks  = (BB * NN) / threads;    // 2048
    tri_sdf_kernel<<<blocks, threads, 0, stream>>>(pss, grid, first, coef, maxl,
                                                   dss, nss, loss);
}